// Round 4
// baseline (116.077 us; speedup 1.0000x reference)
//
#include <hip/hip_runtime.h>

#define IMG_H 512
#define IMG_W 512
#define BATCH 32
#define TW 256            // columns per block (1 col/thread)
#define TH 16             // output rows per block
#define NROWS (TH + 6)    // 22 input rows streamed per tile
#define NTY (IMG_H / TH)  // 32
#define NBLK (2 * NTY * 32)  // 2048 blocks

typedef float f32x2 __attribute__((ext_vector_type(2)));

// gfx950 packed dual-FP32 math (CDNA2+). Non-volatile asm: pure value ops,
// scheduler/CSE stay free. 64-bit "v" operands are even-aligned VGPR pairs.
__device__ __forceinline__ f32x2 pk_fma(f32x2 a, f32x2 b, f32x2 c) {
  f32x2 d;
  asm("v_pk_fma_f32 %0, %1, %2, %3" : "=v"(d) : "v"(a), "v"(b), "v"(c));
  return d;
}
__device__ __forceinline__ f32x2 pk_mul(f32x2 a, f32x2 b) {
  f32x2 d;
  asm("v_pk_mul_f32 %0, %1, %2" : "=v"(d) : "v"(a), "v"(b));
  return d;
}

// Module-scope partials: the harness poisons d_ws regardless, but this keeps
// us independent of it. Fully rewritten every launch before being read.
__device__ float g_partials[NBLK];

__global__ __launch_bounds__(256) void ssim_main(
    const float* __restrict__ X, const float* __restrict__ Y,
    const float* __restrict__ K) {
  __shared__ f32x2 sbuf[2][264];   // x,y interleaved; 262 used
  __shared__ float wsum[4];

  const int t = threadIdx.x;
  const int x0 = blockIdx.x * TW;
  const int y0 = blockIdx.y * TH;
  const size_t img = (size_t)IMG_H * IMG_W;
  const float* Xb = X + blockIdx.z * img;
  const float* Yb = Y + blockIdx.z * img;

  // Exact separable 1D weights from center row of the provided 7x7 kernel:
  // k[3][j] = w3*w_j, sum_j w_j = 1  =>  w_j = k[3][j] / sum_j k[3][j].
  f32x2 w2[7];
  {
    float w[7];
    float rs = 0.f;
#pragma unroll
    for (int j = 0; j < 7; ++j) { w[j] = K[3 * 7 + j]; rs += w[j]; }
    const float inv = 1.f / rs;
#pragma unroll
    for (int j = 0; j < 7; ++j) { w[j] *= inv; w2[j] = (f32x2){w[j], w[j]}; }
  }

  // Loop-invariant horizontal addressing (slot s = image col x0-3+s).
  const int g1 = x0 - 3 + t;
  const bool ok1 = (unsigned)g1 < (unsigned)IMG_W;
  const int g2 = g1 + TW;
  const bool ok2 = (t < 6) && ((unsigned)g2 < (unsigned)IMG_W);

  // mod-7 ring of vertical accumulators: (mu_x,mu_y), (xx,yy), xy.
  f32x2 a01[7], a23[7];
  float a4[7];
#pragma unroll
  for (int s = 0; s < 7; ++s) {
    a01[s] = (f32x2){0.f, 0.f};
    a23[s] = (f32x2){0.f, 0.f};
    a4[s] = 0.f;
  }
  float tsum = 0.f;

  // One-row register prefetch (4 VGPRs; proven no-spill).
  float pxa, pya, pxb, pyb;
  auto load_row = [&](int r) {
    const int gy = y0 - 3 + r;
    pxa = 0.f; pya = 0.f; pxb = 0.f; pyb = 0.f;
    if ((unsigned)gy < (unsigned)IMG_H) {   // wave-uniform
      const float* xrow = Xb + (size_t)gy * IMG_W;
      const float* yrow = Yb + (size_t)gy * IMG_W;
      if (ok1) { pxa = xrow[g1]; pya = yrow[g1]; }
      if (ok2) { pxb = xrow[g2]; pyb = yrow[g2]; }
    }
  };

  load_row(0);

#pragma unroll
  for (int r = 0; r < NROWS; ++r) {   // fully unrolled: r compile-time
    const int buf = r & 1;

    sbuf[buf][t] = (f32x2){pxa, pya};
    if (t < 6) sbuf[buf][TW + t] = (f32x2){pxb, pyb};

    if (r + 1 < NROWS) load_row(r + 1);  // issue next row's global loads

    __syncthreads();

    // horizontal 7-tap, 5 channels packed: 4 VALU + 1 ds_read_b64 per tap
    f32x2 h01 = (f32x2){0.f, 0.f};     // (hx, hy)
    f32x2 h23 = (f32x2){0.f, 0.f};     // (hxx, hyy)
    float h4 = 0.f;                    // hxy
#pragma unroll
    for (int k = 0; k < 7; ++k) {
      const f32x2 p = sbuf[buf][t + k];
      const f32x2 wp = pk_mul(w2[k], p);       // (w*x, w*y)
      h01 = pk_fma(w2[k], p, h01);             // hx += w*x ; hy += w*y
      h23 = pk_fma(wp, p, h23);                // hxx += wx*x ; hyy += wy*y
      h4  = fmaf(wp.x, p.y, h4);               // hxy += wx*y
    }

    // vertical scatter into the ring; guards fold at compile time
#pragma unroll
    for (int tt = 0; tt < 7; ++tt) {
      const int o = r - tt;
      if (o >= 0 && o < TH) {
        const int slot = o % 7;
        a01[slot] = pk_fma(w2[tt], h01, a01[slot]);
        a23[slot] = pk_fma(w2[tt], h23, a23[slot]);
        a4[slot]  = fmaf(w2[tt].x, h4, a4[slot]);
      }
    }

    // output row r-6 complete
    if (r >= 6 && r - 6 < TH) {
      const int slot = (r - 6) % 7;
      const float mu_x = a01[slot].x;
      const float mu_y = a01[slot].y;
      const float mx2 = mu_x * mu_x;
      const float my2 = mu_y * mu_y;
      const float mxy = mu_x * mu_y;
      const float sxx = a23[slot].x - mx2;
      const float syy = a23[slot].y - my2;
      const float sxy = a4[slot] - mxy;
      const float num = (2.f * mxy + 1e-4f) * (2.f * sxy + 9e-4f);
      const float den = (mx2 + my2 + 1e-4f) * (sxx + syy + 9e-4f);
      tsum += num * __builtin_amdgcn_rcpf(den);
      a01[slot] = (f32x2){0.f, 0.f};
      a23[slot] = (f32x2){0.f, 0.f};
      a4[slot] = 0.f;
    }
  }

  // Block reduction -> one plain store per block (no atomics, no fences).
#pragma unroll
  for (int off = 32; off > 0; off >>= 1) tsum += __shfl_down(tsum, off);
  if ((t & 63) == 0) wsum[t >> 6] = tsum;
  __syncthreads();
  if (t == 0) {
    const int bid = blockIdx.x + 2 * (blockIdx.y + NTY * blockIdx.z);
    g_partials[bid] = wsum[0] + wsum[1] + wsum[2] + wsum[3];
  }
}

__global__ __launch_bounds__(256) void ssim_reduce(float* __restrict__ out) {
  __shared__ double wsum[4];
  const int t = threadIdx.x;
  double s = 0.0;
#pragma unroll
  for (int i = 0; i < NBLK / 256; ++i) s += (double)g_partials[t + 256 * i];
#pragma unroll
  for (int off = 32; off > 0; off >>= 1) s += __shfl_down(s, off);
  if ((t & 63) == 0) wsum[t >> 6] = s;
  __syncthreads();
  if (t == 0)
    out[0] = (float)((wsum[0] + wsum[1] + wsum[2] + wsum[3]) *
                     (1.0 / (double)((size_t)BATCH * IMG_H * IMG_W)));
}

extern "C" void kernel_launch(void* const* d_in, const int* in_sizes, int n_in,
                              void* d_out, int out_size, void* d_ws, size_t ws_size,
                              hipStream_t stream) {
  const float* X = (const float*)d_in[0];
  const float* Y = (const float*)d_in[1];
  const float* K = (const float*)d_in[2];
  float* out = (float*)d_out;
  (void)d_ws; (void)ws_size;   // workspace intentionally unused

  dim3 grid(IMG_W / TW, NTY, BATCH);  // (2, 32, 32) = 2048 blocks
  hipLaunchKernelGGL(ssim_main, grid, dim3(256), 0, stream, X, Y, K);
  hipLaunchKernelGGL(ssim_reduce, dim3(1), dim3(256), 0, stream, out);
}

// Round 5
// 110.611 us; speedup vs baseline: 1.0494x; 1.0494x over previous
//
#include <hip/hip_runtime.h>

#define IMG_H 512
#define IMG_W 512
#define BATCH 32
#define TW 256            // columns per block (1 col/thread)
#define TH 16             // output rows per block
#define NROWS (TH + 6)    // 22 input rows streamed per tile
#define NPH (NROWS / 2)   // 11 two-row phases
#define NTY (IMG_H / TH)  // 32
#define NBLK (2 * NTY * 32)  // 2048 blocks

// Module-scope partials: fully rewritten every launch before being read.
__device__ float g_partials[NBLK];

__global__ __launch_bounds__(256) void ssim_main(
    const float* __restrict__ X, const float* __restrict__ Y,
    const float* __restrict__ K) {
  // [phase parity][row-in-pair][col]; one barrier per phase is safe because
  // phase p reads sbuf[p&1] and the next write to that buffer (phase p+2)
  // is separated from those reads by phase p+1's barrier.
  __shared__ float2 sbuf[2][2][264];
  __shared__ float wsum[4];

  const int t = threadIdx.x;
  const int x0 = blockIdx.x * TW;
  const int y0 = blockIdx.y * TH;
  const size_t img = (size_t)IMG_H * IMG_W;
  const float* Xb = X + blockIdx.z * img;
  const float* Yb = Y + blockIdx.z * img;

  // Exact separable 1D weights from center row of the provided 7x7 kernel:
  // k[3][j] = w3*w_j, sum_j w_j = 1  =>  w_j = k[3][j] / sum_j k[3][j].
  float w[7];
  {
    float rs = 0.f;
#pragma unroll
    for (int j = 0; j < 7; ++j) { w[j] = K[3 * 7 + j]; rs += w[j]; }
    const float inv = 1.f / rs;
#pragma unroll
    for (int j = 0; j < 7; ++j) w[j] *= inv;
  }

  // Loop-invariant horizontal addressing (slot s = image col x0-3+s).
  const int g1 = x0 - 3 + t;
  const bool ok1 = (unsigned)g1 < (unsigned)IMG_W;
  const int g2 = g1 + TW;
  const bool ok2 = (t < 6) && ((unsigned)g2 < (unsigned)IMG_W);

  // mod-7 ring of 5-channel vertical accumulators (compile-time indexed).
  float acc[7][5];
#pragma unroll
  for (int s = 0; s < 7; ++s)
#pragma unroll
    for (int c = 0; c < 5; ++c) acc[s][c] = 0.f;
  float tsum = 0.f;

  // Two register prefetch sets x two rows each (16 VGPR). Set s is written
  // to LDS at the top of phase p (s == p&1), reloaded at phase p+1 — a full
  // barrier + 2-row compute of WAR distance.
  float pxa[2][2], pya[2][2], pxb[2][2], pyb[2][2];
  auto load_row = [&](int set, int rr, int r) {
    const int gy = y0 - 3 + r;
    float xa = 0.f, ya = 0.f, xb = 0.f, yb = 0.f;
    if ((unsigned)gy < (unsigned)IMG_H) {   // wave-uniform
      const float* xrow = Xb + (size_t)gy * IMG_W;
      const float* yrow = Yb + (size_t)gy * IMG_W;
      if (ok1) { xa = xrow[g1]; ya = yrow[g1]; }
      if (ok2) { xb = xrow[g2]; yb = yrow[g2]; }
    }
    pxa[set][rr] = xa; pya[set][rr] = ya;
    pxb[set][rr] = xb; pyb[set][rr] = yb;
  };

  load_row(0, 0, 0);
  load_row(0, 1, 1);

#pragma unroll
  for (int ph = 0; ph < NPH; ++ph) {   // fully unrolled: all indices static
    const int set = ph & 1;

    // stage this phase's two rows into LDS
#pragma unroll
    for (int rr = 0; rr < 2; ++rr) {
      sbuf[set][rr][t] = make_float2(pxa[set][rr], pya[set][rr]);
      if (t < 6) sbuf[set][rr][TW + t] = make_float2(pxb[set][rr], pyb[set][rr]);
    }

    // issue next phase's global loads (~2 rows of compute ahead of use)
    if (ph + 1 < NPH) {
      load_row(set ^ 1, 0, 2 * ph + 2);
      load_row(set ^ 1, 1, 2 * ph + 3);
    }

    __syncthreads();

#pragma unroll
    for (int rr = 0; rr < 2; ++rr) {
      const int r = 2 * ph + rr;

      // horizontal 7-tap, 5 channels (7 ds_read_b64)
      float hx = 0.f, hy = 0.f, hxx = 0.f, hyy = 0.f, hxy = 0.f;
#pragma unroll
      for (int k = 0; k < 7; ++k) {
        const float2 p = sbuf[set][rr][t + k];
        const float wx = w[k] * p.x;
        const float wy = w[k] * p.y;
        hx  = fmaf(w[k], p.x, hx);
        hy  = fmaf(w[k], p.y, hy);
        hxx = fmaf(wx, p.x, hxx);
        hyy = fmaf(wy, p.y, hyy);
        hxy = fmaf(wx, p.y, hxy);
      }

      // vertical scatter into the ring; guards fold at compile time
#pragma unroll
      for (int tt = 0; tt < 7; ++tt) {
        const int o = r - tt;
        if (o >= 0 && o < TH) {
          const int slot = o % 7;
          const float wt = w[tt];
          acc[slot][0] = fmaf(wt, hx,  acc[slot][0]);
          acc[slot][1] = fmaf(wt, hy,  acc[slot][1]);
          acc[slot][2] = fmaf(wt, hxx, acc[slot][2]);
          acc[slot][3] = fmaf(wt, hyy, acc[slot][3]);
          acc[slot][4] = fmaf(wt, hxy, acc[slot][4]);
        }
      }

      // output row r-6 complete (r<=21 -> o<=15 < TH)
      if (r >= 6) {
        const int slot = (r - 6) % 7;
        const float mu_x = acc[slot][0];
        const float mu_y = acc[slot][1];
        const float mx2 = mu_x * mu_x;
        const float my2 = mu_y * mu_y;
        const float mxy = mu_x * mu_y;
        const float sxx = acc[slot][2] - mx2;
        const float syy = acc[slot][3] - my2;
        const float sxy = acc[slot][4] - mxy;
        const float num = (2.f * mxy + 1e-4f) * (2.f * sxy + 9e-4f);
        const float den = (mx2 + my2 + 1e-4f) * (sxx + syy + 9e-4f);
        tsum += num * __builtin_amdgcn_rcpf(den);
#pragma unroll
        for (int c = 0; c < 5; ++c) acc[slot][c] = 0.f;
      }
    }
  }

  // Block reduction -> one plain store per block (no atomics, no fences).
#pragma unroll
  for (int off = 32; off > 0; off >>= 1) tsum += __shfl_down(tsum, off);
  if ((t & 63) == 0) wsum[t >> 6] = tsum;
  __syncthreads();
  if (t == 0) {
    const int bid = blockIdx.x + 2 * (blockIdx.y + NTY * blockIdx.z);
    g_partials[bid] = wsum[0] + wsum[1] + wsum[2] + wsum[3];
  }
}

__global__ __launch_bounds__(256) void ssim_reduce(float* __restrict__ out) {
  __shared__ double wsum[4];
  const int t = threadIdx.x;
  double s = 0.0;
#pragma unroll
  for (int i = 0; i < NBLK / 256; ++i) s += (double)g_partials[t + 256 * i];
#pragma unroll
  for (int off = 32; off > 0; off >>= 1) s += __shfl_down(s, off);
  if ((t & 63) == 0) wsum[t >> 6] = s;
  __syncthreads();
  if (t == 0)
    out[0] = (float)((wsum[0] + wsum[1] + wsum[2] + wsum[3]) *
                     (1.0 / (double)((size_t)BATCH * IMG_H * IMG_W)));
}

extern "C" void kernel_launch(void* const* d_in, const int* in_sizes, int n_in,
                              void* d_out, int out_size, void* d_ws, size_t ws_size,
                              hipStream_t stream) {
  const float* X = (const float*)d_in[0];
  const float* Y = (const float*)d_in[1];
  const float* K = (const float*)d_in[2];
  float* out = (float*)d_out;
  (void)d_ws; (void)ws_size;   // workspace intentionally unused

  dim3 grid(IMG_W / TW, NTY, BATCH);  // (2, 32, 32) = 2048 blocks
  hipLaunchKernelGGL(ssim_main, grid, dim3(256), 0, stream, X, Y, K);
  hipLaunchKernelGGL(ssim_reduce, dim3(1), dim3(256), 0, stream, out);
}